// Round 4
// baseline (81.444 us; speedup 1.0000x reference)
//
#include <hip/hip_runtime.h>

#define NN 50
#define D 64

__device__ __forceinline__ float wave_sum64(float x) {
#pragma unroll
  for (int off = 32; off > 0; off >>= 1)
    x += __shfl_xor(x, off, 64);
  return x;
}

__device__ __forceinline__ float readlane_f(float v, int l) {
  return __uint_as_float(__builtin_amdgcn_readlane(__float_as_uint(v), l));
}

__global__ __launch_bounds__(256, 4) void kgat_fwd(
    const int* __restrict__ user_idx, const int* __restrict__ item_idx,
    const int* __restrict__ adj,
    const float* __restrict__ user_tab, const float* __restrict__ item_tab,
    const float* __restrict__ ent_tab,
    const float* __restrict__ attn_W, const float* __restrict__ attn_b,
    const float* __restrict__ W1, const float* __restrict__ b1,
    const float* __restrict__ W2, const float* __restrict__ b2,
    const float* __restrict__ cW, const float* __restrict__ cb,
    const float* __restrict__ oW, const float* __restrict__ ob,
    float* __restrict__ out, int B)
{
  const int lane = threadIdx.x & 63;
  const int wv   = threadIdx.x >> 6;
  const int b    = blockIdx.x * 4 + wv;
  if (b >= B) return;

  // item embedding (lane = dim), kept for phase 7; user row hoisted.
  const float user = user_tab[(long)user_idx[b] * D + lane];
  const float item = item_tab[(long)item_idx[b] * D + lane];
  const float base = wave_sum64(item * attn_W[lane]) + attn_b[0];  // uniform

  const int* adjb = adj + b * NN;

  // ================= score pass: lane n owns neighbor n =================
  // Each lane streams ITS OWN entity row (16 x dwordx4) and dots against
  // Wn held as wave-uniform scalars (literal-index attn_W -> s_load).
  // Scores land one-per-lane: no per-neighbor butterfly reductions.
  const int  myn   = lane < NN ? lane : NN - 1;     // clamp (no OOB adj read)
  int        myidx = adjb[myn];
  myidx = myidx < 0 ? 0 : myidx;
  const float4* myrow = (const float4*)(ent_tab + (size_t)myidx * D);

  float s0 = 0.f, s1 = 0.f, s2 = 0.f, s3 = 0.f;
#pragma unroll
  for (int i = 0; i < 16; ++i) {
    const float4 q = myrow[i];
    s0 = fmaf(q.x, attn_W[D + 4 * i + 0], s0);
    s1 = fmaf(q.y, attn_W[D + 4 * i + 1], s1);
    s2 = fmaf(q.z, attn_W[D + 4 * i + 2], s2);
    s3 = fmaf(q.w, attn_W[D + 4 * i + 3], s3);
  }
  float sc = base + (s0 + s1) + (s2 + s3);
  sc = sc > 0.f ? sc : 0.2f * sc;                   // leaky_relu(0.2)
  // fixed-max softmax: scores are leaky_relu of ~unit-variance dots, bounded
  // well below 8 -> exp(s-8) can't overflow, denom can't underflow to 0.
  float e = (lane < NN) ? __expf(sc - 8.0f) : 0.f;
  const float l = wave_sum64(e);                    // softmax denominator

  // ============ weighted-sum pass: lane = dim, rows are L2-hot ============
  float na0 = 0.f, na1 = 0.f;
#pragma unroll
  for (int g = 0; g < 5; ++g) {
    float vv[10];
#pragma unroll
    for (int i = 0; i < 10; ++i) {
      int t = adjb[g * 10 + i];                     // uniform -> s_load
      t = t < 0 ? 0 : t;
      vv[i] = ent_tab[(size_t)t * D + lane];        // coalesced 256B row
    }
#pragma unroll
    for (int i = 0; i < 10; ++i) {
      const float w = readlane_f(e, g * 10 + i);
      if (i & 1) na1 = fmaf(w, vv[i], na1);
      else       na0 = fmaf(w, vv[i], na0);
    }
  }
  const float na = (na0 + na1) / l;

  // ---- h = relu(na @ W1 + b1): lane owns column, 4-way accumulators ----
  float h0 = b1[lane], h1 = 0.f, h2 = 0.f, h3 = 0.f;
#pragma unroll
  for (int d = 0; d < D; d += 4) {
    h0 = fmaf(readlane_f(na, d + 0), W1[(d + 0) * D + lane], h0);
    h1 = fmaf(readlane_f(na, d + 1), W1[(d + 1) * D + lane], h1);
    h2 = fmaf(readlane_f(na, d + 2), W1[(d + 2) * D + lane], h2);
    h3 = fmaf(readlane_f(na, d + 3), W1[(d + 3) * D + lane], h3);
  }
  const float h = fmaxf((h0 + h1) + (h2 + h3), 0.f);

  // ---- r = h @ W2 + b2 ----
  float r0 = b2[lane], r1 = 0.f, r2 = 0.f, r3 = 0.f;
#pragma unroll
  for (int d = 0; d < D; d += 4) {
    r0 = fmaf(readlane_f(h, d + 0), W2[(d + 0) * D + lane], r0);
    r1 = fmaf(readlane_f(h, d + 1), W2[(d + 1) * D + lane], r1);
    r2 = fmaf(readlane_f(h, d + 2), W2[(d + 2) * D + lane], r2);
    r3 = fmaf(readlane_f(h, d + 3), W2[(d + 3) * D + lane], r3);
  }
  const float r = (r0 + r1) + (r2 + r3);

  // ---- f = relu([item, r] @ cW + cb) ----
  float f0 = cb[lane], f1 = 0.f, f2 = 0.f, f3 = 0.f;
#pragma unroll
  for (int k = 0; k < D; k += 4) {
    f0 = fmaf(readlane_f(item, k + 0), cW[(k + 0) * D + lane], f0);
    f1 = fmaf(readlane_f(item, k + 1), cW[(k + 1) * D + lane], f1);
    f2 = fmaf(readlane_f(item, k + 2), cW[(k + 2) * D + lane], f2);
    f3 = fmaf(readlane_f(item, k + 3), cW[(k + 3) * D + lane], f3);
  }
#pragma unroll
  for (int k = 0; k < D; k += 4) {
    f0 = fmaf(readlane_f(r, k + 0), cW[(D + k + 0) * D + lane], f0);
    f1 = fmaf(readlane_f(r, k + 1), cW[(D + k + 1) * D + lane], f1);
    f2 = fmaf(readlane_f(r, k + 2), cW[(D + k + 2) * D + lane], f2);
    f3 = fmaf(readlane_f(r, k + 3), cW[(D + k + 3) * D + lane], f3);
  }
  const float f = fmaxf((f0 + f1) + (f2 + f3), 0.f);

  // ---- score = dot([user, f], oW) + ob ----
  float out_sc = wave_sum64(fmaf(user, oW[lane], f * oW[D + lane]));
  if (lane == 0) out[b] = out_sc + ob[0];
}

extern "C" void kernel_launch(void* const* d_in, const int* in_sizes, int n_in,
                              void* d_out, int out_size, void* d_ws, size_t ws_size,
                              hipStream_t stream) {
  const int*   user_idx = (const int*)d_in[0];
  const int*   item_idx = (const int*)d_in[1];
  const int*   adj      = (const int*)d_in[2];
  const float* user_tab = (const float*)d_in[3];
  const float* item_tab = (const float*)d_in[4];
  const float* ent_tab  = (const float*)d_in[5];
  const float* attn_W   = (const float*)d_in[6];
  const float* attn_b   = (const float*)d_in[7];
  const float* W1       = (const float*)d_in[8];
  const float* b1       = (const float*)d_in[9];
  const float* W2       = (const float*)d_in[10];
  const float* b2       = (const float*)d_in[11];
  const float* cW       = (const float*)d_in[12];
  const float* cb       = (const float*)d_in[13];
  const float* oW       = (const float*)d_in[14];
  const float* ob       = (const float*)d_in[15];
  float* out = (float*)d_out;

  const int B = in_sizes[0];
  const int blocks = (B + 3) / 4;   // 4 waves (elements) per 256-thread block
  kgat_fwd<<<blocks, 256, 0, stream>>>(user_idx, item_idx, adj,
                                       user_tab, item_tab, ent_tab,
                                       attn_W, attn_b, W1, b1, W2, b2,
                                       cW, cb, oW, ob, out, B);
}